// Round 6
// baseline (294.463 us; speedup 1.0000x reference)
//
#include <hip/hip_runtime.h>
#include <hip/hip_bf16.h>
#include <math.h>

#define N_NODES 50000
#define N_EDGES 800000
#define F_DIM 128
#define H_DIM 64
#define IN_DIM 129   // F_DIM + 1 (binary feature)
#define NPAD 50176   // 196 * 256 (scan-padded node count)
#define WPS 136      // bf16 row stride, proj W  (16B-aligned rows)
#define WOS 72       // bf16 row stride, out W
#define ETOT (N_EDGES + N_NODES)   // 850000 CSR entries (self-loop per node)

typedef __hip_bfloat16 bf16;
typedef __attribute__((ext_vector_type(8))) short bf16x8;   // MFMA A/B frag (4 VGPR)
typedef __attribute__((ext_vector_type(4))) float f32x4;    // MFMA C/D frag

static __device__ __forceinline__ float b2f(bf16 x) { return __bfloat162float(x); }
static __device__ __forceinline__ float bs2f(short s) {
    union { float f; unsigned u; } c; c.u = ((unsigned)(unsigned short)s) << 16; return c.f;
}
static __device__ __forceinline__ short f2bs(float f) {
    union { bf16 b; short s; } u; u.b = __float2bfloat16(f); return u.s;
}

// ---------------------------------------------------------------------------
// P0: split W matrices into bf16 hi/lo (hi+lo ~ f32 exact, err ~2^-17),
// stack [Wl;Wr] -> 128 rows x 129, col 128 kept f32 (wcol), bias stacked.
// ---------------------------------------------------------------------------
__global__ __launch_bounds__(256) void prep_kernel(
    const float* __restrict__ Wl, const float* __restrict__ bl,
    const float* __restrict__ Wr, const float* __restrict__ br,
    const float* __restrict__ Wo,
    bf16* __restrict__ wphi, bf16* __restrict__ wplo,
    float* __restrict__ wcol, float* __restrict__ biasP,
    bf16* __restrict__ wohi, bf16* __restrict__ wolo)
{
    int tid  = blockIdx.x * 256 + threadIdx.x;
    int nthr = gridDim.x * 256;
    for (int idx = tid; idx < 128 * IN_DIM; idx += nthr) {
        int r = idx / IN_DIM, k = idx - r * IN_DIM;
        float v = (r < 64) ? Wl[r * IN_DIM + k] : Wr[(r - 64) * IN_DIM + k];
        if (k == 128) {
            wcol[r] = v;
        } else {
            bf16 hi = __float2bfloat16(v);
            wphi[r * WPS + k] = hi;
            wplo[r * WPS + k] = __float2bfloat16(v - b2f(hi));
        }
    }
    for (int idx = tid; idx < 128 * 64; idx += nthr) {
        int r = idx >> 6, k = idx & 63;
        float v = Wo[idx];
        bf16 hi = __float2bfloat16(v);
        wohi[r * WOS + k] = hi;
        wolo[r * WOS + k] = __float2bfloat16(v - b2f(hi));
    }
    if (tid < 128) biasP[tid] = (tid < 64) ? bl[tid] : br[tid - 64];
}

// ---------------------------------------------------------------------------
// K1 (MFMA): [xl|xr] = x @ [Wl;Wr]^T + bias.  B-frags in registers, no LDS.
// ---------------------------------------------------------------------------
__global__ __launch_bounds__(256) void proj_mfma(
    const float* __restrict__ xf, const float* __restrict__ xb,
    const bf16* __restrict__ wphi, const bf16* __restrict__ wplo,
    const float* __restrict__ wcol, const float* __restrict__ biasP,
    bf16* __restrict__ xl, bf16* __restrict__ xr)
{
    int wave = threadIdx.x >> 6;
    int lane = threadIdx.x & 63;
    int n = lane & 15, q = lane >> 4;
    int node0 = blockIdx.x * 64;

    bf16x8 bhi[2][4], blo[2][4];
    float biasv[2], w128[2];
    #pragma unroll
    for (int nt = 0; nt < 2; ++nt) {
        int ch = wave * 32 + nt * 16 + n;
        #pragma unroll
        for (int ks = 0; ks < 4; ++ks) {
            bhi[nt][ks] = *(const bf16x8*)(wphi + ch * WPS + ks * 32 + q * 8);
            blo[nt][ks] = *(const bf16x8*)(wplo + ch * WPS + ks * 32 + q * 8);
        }
        biasv[nt] = biasP[ch];
        w128[nt]  = wcol[ch];
    }

    #pragma unroll
    for (int mt = 0; mt < 4; ++mt) {
        int nb = node0 + mt * 16;
        if (nb >= N_NODES) break;
        const float* xrow = xf + (size_t)(nb + n) * F_DIM;
        bf16x8 a[4];
        #pragma unroll
        for (int ks = 0; ks < 4; ++ks) {
            float4 u = *(const float4*)(xrow + ks * 32 + q * 8);
            float4 v = *(const float4*)(xrow + ks * 32 + q * 8 + 4);
            bf16x8 t;
            t[0] = f2bs(u.x); t[1] = f2bs(u.y); t[2] = f2bs(u.z); t[3] = f2bs(u.w);
            t[4] = f2bs(v.x); t[5] = f2bs(v.y); t[6] = f2bs(v.z); t[7] = f2bs(v.w);
            a[ks] = t;
        }
        f32x4 acc[2] = {{0.f,0.f,0.f,0.f},{0.f,0.f,0.f,0.f}};
        #pragma unroll
        for (int ks = 0; ks < 4; ++ks) {
            #pragma unroll
            for (int nt = 0; nt < 2; ++nt) {
                acc[nt] = __builtin_amdgcn_mfma_f32_16x16x32_bf16(a[ks], bhi[nt][ks], acc[nt], 0, 0, 0);
                acc[nt] = __builtin_amdgcn_mfma_f32_16x16x32_bf16(a[ks], blo[nt][ks], acc[nt], 0, 0, 0);
            }
        }
        float4 xbv = *(const float4*)(xb + nb + q * 4);
        float xbr[4] = {xbv.x, xbv.y, xbv.z, xbv.w};
        #pragma unroll
        for (int nt = 0; nt < 2; ++nt) {
            int ch = wave * 32 + nt * 16 + n;
            bf16* dstp = (ch < 64) ? xl : xr;
            int cc = ch & 63;
            #pragma unroll
            for (int r = 0; r < 4; ++r) {
                int node = nb + q * 4 + r;   // C/D: row = quad*4 + reg
                float val = acc[nt][r] + xbr[r] * w128[nt] + biasv[nt];
                dstp[(size_t)node * H_DIM + cc] = __float2bfloat16(val);
            }
        }
    }
}

// ---------------------------------------------------------------------------
// CSR build. Self-loop slot is embedded by scanning (deg+1), reserving
// position offs[n] for node n's self edge; real edges go to offs[dst]+1+k.
// ---------------------------------------------------------------------------
__global__ __launch_bounds__(256) void count_kernel(
    const int* __restrict__ edst, int* __restrict__ cnt)
{
    int e = blockIdx.x * 256 + threadIdx.x;
    if (e < N_EDGES) atomicAdd(&cnt[edst[e]], 1);
}

__global__ __launch_bounds__(256) void scan_a_kernel(
    const int* __restrict__ cnt, int* __restrict__ offs, int* __restrict__ bsum)
{
    __shared__ int s[256];
    int tid = threadIdx.x;
    int i = blockIdx.x * 256 + tid;
    int v = (i < N_NODES) ? cnt[i] + 1 : 0;    // +1 = self-loop slot
    s[tid] = v;
    __syncthreads();
    #pragma unroll
    for (int d = 1; d < 256; d <<= 1) {
        int t = (tid >= d) ? s[tid - d] : 0;
        __syncthreads();
        s[tid] += t;
        __syncthreads();
    }
    offs[i] = s[tid] - v;
    if (tid == 255) bsum[blockIdx.x] = s[255];
}

__global__ __launch_bounds__(256) void scan_b_kernel(int* __restrict__ bsum)
{
    __shared__ int s[256];
    int tid = threadIdx.x;
    int v = (tid < 196) ? bsum[tid] : 0;
    s[tid] = v;
    __syncthreads();
    #pragma unroll
    for (int d = 1; d < 256; d <<= 1) {
        int t = (tid >= d) ? s[tid - d] : 0;
        __syncthreads();
        s[tid] += t;
        __syncthreads();
    }
    if (tid < 196) bsum[tid] = s[tid] - v;
}

__global__ __launch_bounds__(256) void scan_c_kernel(
    int* __restrict__ offs, const int* __restrict__ bsum)
{
    int i = blockIdx.x * 256 + threadIdx.x;
    offs[i] += bsum[blockIdx.x];
}

// ---------------------------------------------------------------------------
// K2a (fused CSR-fill + edge score, lane-per-edge, NO cross-lane ops):
// id < E: real edge (placement via atomic); else self-loop of node id-E
// (slot offs[n]). Each lane computes the full 64-ch dot in registers:
//   p = att . leakyrelu(xl[src] + xr[dst]);  ex[pos] = exp(p)
// att broadcast from LDS (same-address reads are free).
// ---------------------------------------------------------------------------
__global__ __launch_bounds__(256) void fill_score_kernel(
    const int* __restrict__ esrc, const int* __restrict__ edst,
    const int* __restrict__ offs, int* __restrict__ cur,
    const bf16* __restrict__ xl, const bf16* __restrict__ xr,
    const float* __restrict__ att,
    int* __restrict__ csr_src, float* __restrict__ exv)
{
    __shared__ float satt[64];
    if (threadIdx.x < 64) satt[threadIdx.x] = att[threadIdx.x];
    __syncthreads();

    int id = blockIdx.x * 256 + threadIdx.x;
    if (id >= ETOT) return;

    int src, dst, pos;
    if (id < N_EDGES) {
        src = esrc[id];
        dst = edst[id];
        pos = offs[dst] + 1 + atomicAdd(&cur[dst], 1);
    } else {
        src = dst = id - N_EDGES;
        pos = offs[src];
    }
    csr_src[pos] = src;

    const bf16x8* xl8 = (const bf16x8*)xl;
    const bf16x8* xr8 = (const bf16x8*)xr;
    float p = 0.f;
    #pragma unroll
    for (int c = 0; c < 8; ++c) {
        bf16x8 a = xl8[(size_t)src * 8 + c];
        bf16x8 b = xr8[(size_t)dst * 8 + c];
        #pragma unroll
        for (int j = 0; j < 8; ++j) {
            float m = bs2f(a[j]) + bs2f(b[j]);
            m = (m > 0.f) ? m : 0.2f * m;
            p += m * satt[c * 8 + j];
        }
    }
    exv[pos] = __expf(p);
}

// ---------------------------------------------------------------------------
// K2b: aggregation, wave-per-dst, no atomics, NO cross-lane ops.
//   den = sum(ex); acc[lane] = sum(ex_i * xl[src_i][lane])
// 4-edge batches keep 4 independent gathers in flight (latency/4).
// ---------------------------------------------------------------------------
__global__ __launch_bounds__(256) void agg2_kernel(
    const int* __restrict__ csr_src, const float* __restrict__ exv,
    const int* __restrict__ offs,
    const bf16* __restrict__ xl, const float* __restrict__ gb,
    bf16* __restrict__ h)
{
    int wid  = (blockIdx.x * 256 + threadIdx.x) >> 6;   // dst node
    int lane = threadIdx.x & 63;
    if (wid >= N_NODES) return;

    int beg = offs[wid], end = offs[wid + 1];
    float den = 0.f, acc = 0.f;
    int i = beg;
    for (; i + 4 <= end; i += 4) {
        int s0 = csr_src[i],     s1 = csr_src[i + 1];
        int s2 = csr_src[i + 2], s3 = csr_src[i + 3];
        float e0 = exv[i],     e1 = exv[i + 1];
        float e2 = exv[i + 2], e3 = exv[i + 3];
        float x0 = b2f(xl[(size_t)s0 * H_DIM + lane]);
        float x1 = b2f(xl[(size_t)s1 * H_DIM + lane]);
        float x2 = b2f(xl[(size_t)s2 * H_DIM + lane]);
        float x3 = b2f(xl[(size_t)s3 * H_DIM + lane]);
        den += (e0 + e1) + (e2 + e3);
        acc += e0 * x0 + e1 * x1 + e2 * x2 + e3 * x3;
    }
    for (; i < end; ++i) {
        int s = csr_src[i];
        float e = exv[i];
        acc += e * b2f(xl[(size_t)s * H_DIM + lane]);
        den += e;
    }

    float v = acc / den + gb[lane];
    v = (v > 0.f) ? v : expm1f(v);
    h[(size_t)wid * H_DIM + lane] = __float2bfloat16(v);
}

// ---------------------------------------------------------------------------
// K3 (MFMA): logits = h @ Wo^T + bo (+ softplus(dispersion) tail on block 0).
// ---------------------------------------------------------------------------
__global__ __launch_bounds__(256) void out_mfma(
    const bf16* __restrict__ h,
    const bf16* __restrict__ wohi, const bf16* __restrict__ wolo,
    const float* __restrict__ bo, const float* __restrict__ disp,
    float* __restrict__ out)
{
    if (blockIdx.x == 0 && threadIdx.x < F_DIM) {
        float d = disp[threadIdx.x];
        out[(size_t)N_NODES * F_DIM + threadIdx.x] = (d > 20.f) ? d : log1pf(__expf(d));
    }

    int wave = threadIdx.x >> 6;
    int lane = threadIdx.x & 63;
    int n = lane & 15, q = lane >> 4;
    int node0 = blockIdx.x * 64;

    bf16x8 bhi[2][2], blo[2][2];
    float bov[2];
    #pragma unroll
    for (int nt = 0; nt < 2; ++nt) {
        int ch = wave * 32 + nt * 16 + n;
        #pragma unroll
        for (int ks = 0; ks < 2; ++ks) {
            bhi[nt][ks] = *(const bf16x8*)(wohi + ch * WOS + ks * 32 + q * 8);
            blo[nt][ks] = *(const bf16x8*)(wolo + ch * WOS + ks * 32 + q * 8);
        }
        bov[nt] = bo[ch];
    }

    #pragma unroll
    for (int mt = 0; mt < 4; ++mt) {
        int nb = node0 + mt * 16;
        if (nb >= N_NODES) break;
        const bf16* hrow = h + (size_t)(nb + n) * H_DIM;
        bf16x8 a[2];
        #pragma unroll
        for (int ks = 0; ks < 2; ++ks)
            a[ks] = *(const bf16x8*)(hrow + ks * 32 + q * 8);
        f32x4 acc[2] = {{0.f,0.f,0.f,0.f},{0.f,0.f,0.f,0.f}};
        #pragma unroll
        for (int ks = 0; ks < 2; ++ks) {
            #pragma unroll
            for (int nt = 0; nt < 2; ++nt) {
                acc[nt] = __builtin_amdgcn_mfma_f32_16x16x32_bf16(a[ks], bhi[nt][ks], acc[nt], 0, 0, 0);
                acc[nt] = __builtin_amdgcn_mfma_f32_16x16x32_bf16(a[ks], blo[nt][ks], acc[nt], 0, 0, 0);
            }
        }
        #pragma unroll
        for (int nt = 0; nt < 2; ++nt) {
            int ch = wave * 32 + nt * 16 + n;
            #pragma unroll
            for (int r = 0; r < 4; ++r) {
                int node = nb + q * 4 + r;
                out[(size_t)node * F_DIM + ch] = acc[nt][r] + bov[nt];
            }
        }
    }
}

// ---------------------------------------------------------------------------
extern "C" void kernel_launch(void* const* d_in, const int* in_sizes, int n_in,
                              void* d_out, int out_size, void* d_ws, size_t ws_size,
                              hipStream_t stream)
{
    const float* xf  = (const float*)d_in[0];
    const float* xb  = (const float*)d_in[1];
    const int*   ei  = (const int*)d_in[2];    // [2, E] int32, row-major
    const float* Wl  = (const float*)d_in[3];
    const float* bl  = (const float*)d_in[4];
    const float* Wr  = (const float*)d_in[5];
    const float* br  = (const float*)d_in[6];
    const float* att = (const float*)d_in[7];
    const float* gb  = (const float*)d_in[8];
    const float* Wo  = (const float*)d_in[9];
    const float* bo  = (const float*)d_in[10];
    const float* dp  = (const float*)d_in[11];
    float* out = (float*)d_out;
    const int* esrc = ei;
    const int* edst = ei + N_EDGES;

    // ws layout (16B-aligned segments):
    //  xl bf16[N*64] | xr bf16[N*64] | h bf16[N*64] | csr_src int[ETOT] |
    //  exv f32[ETOT] | cnt int[NPAD] | cur int[NPAD] | offs int[NPAD] |
    //  bsum int[256] | wphi/wplo | wohi/wolo | wcol f32[128] | biasP f32[128]
    char* ws = (char*)d_ws;
    const size_t SZB = (size_t)N_NODES * H_DIM * sizeof(bf16);   // 6.4 MB
    bf16*  xl      = (bf16*)(ws);
    bf16*  xr      = (bf16*)(ws + SZB);
    bf16*  h       = (bf16*)(ws + 2 * SZB);
    int*   csr_src = (int*)(ws + 3 * SZB);
    float* exv     = (float*)(ws + 3 * SZB + (size_t)ETOT * 4);
    int*   cnt     = (int*)(ws + 3 * SZB + 2 * (size_t)ETOT * 4);
    int*   cur     = cnt + NPAD;
    int*   offs    = cur + NPAD;
    int*   bsum    = offs + NPAD;
    bf16*  wphi    = (bf16*)(bsum + 256);
    bf16*  wplo    = wphi + 128 * WPS;
    bf16*  wohi    = wplo + 128 * WPS;
    bf16*  wolo    = wohi + 128 * WOS;
    float* wcol    = (float*)(wolo + 128 * WOS);
    float* biasP   = wcol + 128;

    hipMemsetAsync(cnt, 0, 2 * NPAD * sizeof(int), stream);

    prep_kernel<<<32, 256, 0, stream>>>(Wl, bl, Wr, br, Wo,
                                        wphi, wplo, wcol, biasP, wohi, wolo);

    proj_mfma<<<(N_NODES + 63) / 64, 256, 0, stream>>>(xf, xb, wphi, wplo,
                                                       wcol, biasP, xl, xr);

    count_kernel<<<N_EDGES / 256, 256, 0, stream>>>(edst, cnt);
    scan_a_kernel<<<NPAD / 256, 256, 0, stream>>>(cnt, offs, bsum);
    scan_b_kernel<<<1, 256, 0, stream>>>(bsum);
    scan_c_kernel<<<NPAD / 256, 256, 0, stream>>>(offs, bsum);

    fill_score_kernel<<<(ETOT + 255) / 256, 256, 0, stream>>>(
        esrc, edst, offs, cur, xl, xr, att, csr_src, exv);

    agg2_kernel<<<(N_NODES * 64) / 256, 256, 0, stream>>>(csr_src, exv, offs,
                                                          xl, gb, h);

    out_mfma<<<(N_NODES + 63) / 64, 256, 0, stream>>>(h, wohi, wolo, bo, dp, out);
}

// Round 7
// 250.941 us; speedup vs baseline: 1.1734x; 1.1734x over previous
//
#include <hip/hip_runtime.h>
#include <hip/hip_bf16.h>
#include <math.h>

#define N_NODES 50000
#define N_EDGES 800000
#define F_DIM 128
#define H_DIM 64
#define IN_DIM 129   // F_DIM + 1 (binary feature)
#define NPAD 50176   // 196 * 256 (scan-padded node count)
#define WPS 136      // bf16 row stride, proj W  (16B-aligned rows)
#define WOS 72       // bf16 row stride, out W
#define ETOT (N_EDGES + N_NODES)   // 850000 CSR entries (self-loop per node)

typedef __hip_bfloat16 bf16;
typedef __attribute__((ext_vector_type(8))) short bf16x8;   // MFMA A/B frag (4 VGPR)
typedef __attribute__((ext_vector_type(4))) float f32x4;    // MFMA C/D frag

static __device__ __forceinline__ float b2f(bf16 x) { return __bfloat162float(x); }
static __device__ __forceinline__ float bs2f(short s) {
    union { float f; unsigned u; } c; c.u = ((unsigned)(unsigned short)s) << 16; return c.f;
}
static __device__ __forceinline__ short f2bs(float f) {
    union { bf16 b; short s; } u; u.b = __float2bfloat16(f); return u.s;
}

// ---------------------------------------------------------------------------
// P0 (merged prep + degree count): W hi/lo split for MFMA, stacked bias, and
// the CSR degree histogram — independent work, one dispatch.
// ---------------------------------------------------------------------------
__global__ __launch_bounds__(256) void prep_count_kernel(
    const float* __restrict__ Wl, const float* __restrict__ bl,
    const float* __restrict__ Wr, const float* __restrict__ br,
    const float* __restrict__ Wo, const int* __restrict__ edst,
    bf16* __restrict__ wphi, bf16* __restrict__ wplo,
    float* __restrict__ wcol, float* __restrict__ biasP,
    bf16* __restrict__ wohi, bf16* __restrict__ wolo,
    int* __restrict__ cnt)
{
    int tid  = blockIdx.x * 256 + threadIdx.x;
    int nthr = gridDim.x * 256;

    if (tid < N_EDGES) atomicAdd(&cnt[edst[tid]], 1);   // grid sized for this

    for (int idx = tid; idx < 128 * IN_DIM; idx += nthr) {
        int r = idx / IN_DIM, k = idx - r * IN_DIM;
        float v = (r < 64) ? Wl[r * IN_DIM + k] : Wr[(r - 64) * IN_DIM + k];
        if (k == 128) {
            wcol[r] = v;
        } else {
            bf16 hi = __float2bfloat16(v);
            wphi[r * WPS + k] = hi;
            wplo[r * WPS + k] = __float2bfloat16(v - b2f(hi));
        }
    }
    for (int idx = tid; idx < 128 * 64; idx += nthr) {
        int r = idx >> 6, k = idx & 63;
        float v = Wo[idx];
        bf16 hi = __float2bfloat16(v);
        wohi[r * WOS + k] = hi;
        wolo[r * WOS + k] = __float2bfloat16(v - b2f(hi));
    }
    if (tid < 128) biasP[tid] = (tid < 64) ? bl[tid] : br[tid - 64];
}

// ---------------------------------------------------------------------------
// K1 (MFMA): [xl|xr] = x @ [Wl;Wr]^T + bias.  B-frags in registers, no LDS.
// ---------------------------------------------------------------------------
__global__ __launch_bounds__(256) void proj_mfma(
    const float* __restrict__ xf, const float* __restrict__ xb,
    const bf16* __restrict__ wphi, const bf16* __restrict__ wplo,
    const float* __restrict__ wcol, const float* __restrict__ biasP,
    bf16* __restrict__ xl, bf16* __restrict__ xr)
{
    int wave = threadIdx.x >> 6;
    int lane = threadIdx.x & 63;
    int n = lane & 15, q = lane >> 4;
    int node0 = blockIdx.x * 64;

    bf16x8 bhi[2][4], blo[2][4];
    float biasv[2], w128[2];
    #pragma unroll
    for (int nt = 0; nt < 2; ++nt) {
        int ch = wave * 32 + nt * 16 + n;
        #pragma unroll
        for (int ks = 0; ks < 4; ++ks) {
            bhi[nt][ks] = *(const bf16x8*)(wphi + ch * WPS + ks * 32 + q * 8);
            blo[nt][ks] = *(const bf16x8*)(wplo + ch * WPS + ks * 32 + q * 8);
        }
        biasv[nt] = biasP[ch];
        w128[nt]  = wcol[ch];
    }

    #pragma unroll
    for (int mt = 0; mt < 4; ++mt) {
        int nb = node0 + mt * 16;
        if (nb >= N_NODES) break;
        const float* xrow = xf + (size_t)(nb + n) * F_DIM;
        bf16x8 a[4];
        #pragma unroll
        for (int ks = 0; ks < 4; ++ks) {
            float4 u = *(const float4*)(xrow + ks * 32 + q * 8);
            float4 v = *(const float4*)(xrow + ks * 32 + q * 8 + 4);
            bf16x8 t;
            t[0] = f2bs(u.x); t[1] = f2bs(u.y); t[2] = f2bs(u.z); t[3] = f2bs(u.w);
            t[4] = f2bs(v.x); t[5] = f2bs(v.y); t[6] = f2bs(v.z); t[7] = f2bs(v.w);
            a[ks] = t;
        }
        f32x4 acc[2] = {{0.f,0.f,0.f,0.f},{0.f,0.f,0.f,0.f}};
        #pragma unroll
        for (int ks = 0; ks < 4; ++ks) {
            #pragma unroll
            for (int nt = 0; nt < 2; ++nt) {
                acc[nt] = __builtin_amdgcn_mfma_f32_16x16x32_bf16(a[ks], bhi[nt][ks], acc[nt], 0, 0, 0);
                acc[nt] = __builtin_amdgcn_mfma_f32_16x16x32_bf16(a[ks], blo[nt][ks], acc[nt], 0, 0, 0);
            }
        }
        float4 xbv = *(const float4*)(xb + nb + q * 4);
        float xbr[4] = {xbv.x, xbv.y, xbv.z, xbv.w};
        #pragma unroll
        for (int nt = 0; nt < 2; ++nt) {
            int ch = wave * 32 + nt * 16 + n;
            bf16* dstp = (ch < 64) ? xl : xr;
            int cc = ch & 63;
            #pragma unroll
            for (int r = 0; r < 4; ++r) {
                int node = nb + q * 4 + r;   // C/D: row = quad*4 + reg
                float val = acc[nt][r] + xbr[r] * w128[nt] + biasv[nt];
                dstp[(size_t)node * H_DIM + cc] = __float2bfloat16(val);
            }
        }
    }
}

// ---------------------------------------------------------------------------
// CSR scan (deg+1 per node: slot offs[n] reserved for the self-loop).
// ---------------------------------------------------------------------------
__global__ __launch_bounds__(256) void scan_a_kernel(
    const int* __restrict__ cnt, int* __restrict__ offs, int* __restrict__ bsum)
{
    __shared__ int s[256];
    int tid = threadIdx.x;
    int i = blockIdx.x * 256 + tid;
    int v = (i < N_NODES) ? cnt[i] + 1 : 0;    // +1 = self-loop slot
    s[tid] = v;
    __syncthreads();
    #pragma unroll
    for (int d = 1; d < 256; d <<= 1) {
        int t = (tid >= d) ? s[tid - d] : 0;
        __syncthreads();
        s[tid] += t;
        __syncthreads();
    }
    offs[i] = s[tid] - v;
    if (tid == 255) bsum[blockIdx.x] = s[255];
}

__global__ __launch_bounds__(256) void scan_b_kernel(int* __restrict__ bsum)
{
    __shared__ int s[256];
    int tid = threadIdx.x;
    int v = (tid < 196) ? bsum[tid] : 0;
    s[tid] = v;
    __syncthreads();
    #pragma unroll
    for (int d = 1; d < 256; d <<= 1) {
        int t = (tid >= d) ? s[tid - d] : 0;
        __syncthreads();
        s[tid] += t;
        __syncthreads();
    }
    if (tid < 196) bsum[tid] = s[tid] - v;
}

__global__ __launch_bounds__(256) void scan_c_kernel(
    int* __restrict__ offs, const int* __restrict__ bsum)
{
    int i = blockIdx.x * 256 + threadIdx.x;
    offs[i] += bsum[blockIdx.x];
}

// ---------------------------------------------------------------------------
// K2a: CSR fill. id < E: real edge (slot offs[dst]+1+cur++); id >= E:
// self-loop of node id-E at slot offs[n].
// ---------------------------------------------------------------------------
__global__ __launch_bounds__(256) void fill_kernel(
    const int* __restrict__ esrc, const int* __restrict__ edst,
    const int* __restrict__ offs, int* __restrict__ cur,
    int* __restrict__ csr_src)
{
    int id = blockIdx.x * 256 + threadIdx.x;
    if (id >= ETOT) return;
    int src, pos;
    if (id < N_EDGES) {
        src = esrc[id];
        int dst = edst[id];
        pos = offs[dst] + 1 + atomicAdd(&cur[dst], 1);
    } else {
        src = id - N_EDGES;
        pos = offs[src];
    }
    csr_src[pos] = src;
}

// ---------------------------------------------------------------------------
// K2b (fused score + aggregate, ONE gather per edge, wave-per-dst):
// 2-D lane layout: g = lane>>3 (edge slot, 8 edges/batch), c8 = lane&7
// (channel octet). Lane (g,c8) loads 16 B of edge g's xl row -> per-row
// coalesced. Dot reduce = 3 shfl_xor (1,2,4) per BATCH (all 8 groups at
// once); group-combine (xor 8,16,32) once per dst. ex=0 masks tail slots.
// Next-batch gather is prefetched (clamped index, always in-bounds).
// ---------------------------------------------------------------------------
__global__ __launch_bounds__(256) void agg_fused(
    const int* __restrict__ csr_src, const int* __restrict__ offs,
    const bf16* __restrict__ xl, const bf16* __restrict__ xr,
    const float* __restrict__ att, const float* __restrict__ gb,
    bf16* __restrict__ h)
{
    int wid  = (blockIdx.x * 256 + threadIdx.x) >> 6;   // dst node
    int lane = threadIdx.x & 63;
    if (wid >= N_NODES) return;
    int g  = lane >> 3;   // edge slot within batch
    int c8 = lane & 7;    // channel octet

    float attv[8], xrv[8];
    {
        bf16x8 xrow = *(const bf16x8*)(xr + (size_t)wid * H_DIM + c8 * 8);
        float4 a0 = *(const float4*)(att + c8 * 8);
        float4 a1 = *(const float4*)(att + c8 * 8 + 4);
        attv[0] = a0.x; attv[1] = a0.y; attv[2] = a0.z; attv[3] = a0.w;
        attv[4] = a1.x; attv[5] = a1.y; attv[6] = a1.z; attv[7] = a1.w;
        #pragma unroll
        for (int j = 0; j < 8; ++j) xrv[j] = bs2f(xrow[j]);
    }

    int beg = offs[wid], end = offs[wid + 1];   // end-beg >= 1 (self-loop)
    int last = end - 1;
    float den = 0.f;
    float acc[8] = {0.f, 0.f, 0.f, 0.f, 0.f, 0.f, 0.f, 0.f};

    int e0 = beg + g;
    int src0 = csr_src[(e0 < end) ? e0 : last];
    bf16x8 xa = *(const bf16x8*)(xl + (size_t)src0 * H_DIM + c8 * 8);

    for (int base = beg; base < end; base += 8) {
        // prefetch next batch (clamped -> always in-bounds, harmless extra)
        int en = base + 8 + g;
        int srcn = csr_src[(en < end) ? en : last];
        bf16x8 xan = *(const bf16x8*)(xl + (size_t)srcn * H_DIM + c8 * 8);

        bool valid = (base + g) < end;
        float xv[8], p = 0.f;
        #pragma unroll
        for (int j = 0; j < 8; ++j) {
            xv[j] = bs2f(xa[j]);
            float m = xv[j] + xrv[j];
            m = (m > 0.f) ? m : 0.2f * m;
            p += m * attv[j];
        }
        p += __shfl_xor(p, 1);
        p += __shfl_xor(p, 2);
        p += __shfl_xor(p, 4);      // all lanes of group g now hold p_g
        float ex = valid ? __expf(p) : 0.f;
        den += ex;
        #pragma unroll
        for (int j = 0; j < 8; ++j) acc[j] += ex * xv[j];

        xa = xan;
    }

    // combine the 8 edge-groups (once per dst)
    #pragma unroll
    for (int j = 0; j < 8; ++j) {
        acc[j] += __shfl_xor(acc[j], 8);
        acc[j] += __shfl_xor(acc[j], 16);
        acc[j] += __shfl_xor(acc[j], 32);
    }
    den += __shfl_xor(den, 8);
    den += __shfl_xor(den, 16);
    den += __shfl_xor(den, 32);

    if (g == 0) {
        float inv = 1.0f / den;
        float4 g0 = *(const float4*)(gb + c8 * 8);
        float4 g1 = *(const float4*)(gb + c8 * 8 + 4);
        float gbv[8] = {g0.x, g0.y, g0.z, g0.w, g1.x, g1.y, g1.z, g1.w};
        bf16x8 ov;
        #pragma unroll
        for (int j = 0; j < 8; ++j) {
            float v = acc[j] * inv + gbv[j];
            v = (v > 0.f) ? v : expm1f(v);
            ov[j] = f2bs(v);
        }
        *(bf16x8*)(h + (size_t)wid * H_DIM + c8 * 8) = ov;
    }
}

// ---------------------------------------------------------------------------
// K3 (MFMA): logits = h @ Wo^T + bo (+ softplus(dispersion) tail on block 0).
// ---------------------------------------------------------------------------
__global__ __launch_bounds__(256) void out_mfma(
    const bf16* __restrict__ h,
    const bf16* __restrict__ wohi, const bf16* __restrict__ wolo,
    const float* __restrict__ bo, const float* __restrict__ disp,
    float* __restrict__ out)
{
    if (blockIdx.x == 0 && threadIdx.x < F_DIM) {
        float d = disp[threadIdx.x];
        out[(size_t)N_NODES * F_DIM + threadIdx.x] = (d > 20.f) ? d : log1pf(__expf(d));
    }

    int wave = threadIdx.x >> 6;
    int lane = threadIdx.x & 63;
    int n = lane & 15, q = lane >> 4;
    int node0 = blockIdx.x * 64;

    bf16x8 bhi[2][2], blo[2][2];
    float bov[2];
    #pragma unroll
    for (int nt = 0; nt < 2; ++nt) {
        int ch = wave * 32 + nt * 16 + n;
        #pragma unroll
        for (int ks = 0; ks < 2; ++ks) {
            bhi[nt][ks] = *(const bf16x8*)(wohi + ch * WOS + ks * 32 + q * 8);
            blo[nt][ks] = *(const bf16x8*)(wolo + ch * WOS + ks * 32 + q * 8);
        }
        bov[nt] = bo[ch];
    }

    #pragma unroll
    for (int mt = 0; mt < 4; ++mt) {
        int nb = node0 + mt * 16;
        if (nb >= N_NODES) break;
        const bf16* hrow = h + (size_t)(nb + n) * H_DIM;
        bf16x8 a[2];
        #pragma unroll
        for (int ks = 0; ks < 2; ++ks)
            a[ks] = *(const bf16x8*)(hrow + ks * 32 + q * 8);
        f32x4 acc[2] = {{0.f,0.f,0.f,0.f},{0.f,0.f,0.f,0.f}};
        #pragma unroll
        for (int ks = 0; ks < 2; ++ks) {
            #pragma unroll
            for (int nt = 0; nt < 2; ++nt) {
                acc[nt] = __builtin_amdgcn_mfma_f32_16x16x32_bf16(a[ks], bhi[nt][ks], acc[nt], 0, 0, 0);
                acc[nt] = __builtin_amdgcn_mfma_f32_16x16x32_bf16(a[ks], blo[nt][ks], acc[nt], 0, 0, 0);
            }
        }
        #pragma unroll
        for (int nt = 0; nt < 2; ++nt) {
            int ch = wave * 32 + nt * 16 + n;
            #pragma unroll
            for (int r = 0; r < 4; ++r) {
                int node = nb + q * 4 + r;
                out[(size_t)node * F_DIM + ch] = acc[nt][r] + bov[nt];
            }
        }
    }
}

// ---------------------------------------------------------------------------
extern "C" void kernel_launch(void* const* d_in, const int* in_sizes, int n_in,
                              void* d_out, int out_size, void* d_ws, size_t ws_size,
                              hipStream_t stream)
{
    const float* xf  = (const float*)d_in[0];
    const float* xb  = (const float*)d_in[1];
    const int*   ei  = (const int*)d_in[2];    // [2, E] int32, row-major
    const float* Wl  = (const float*)d_in[3];
    const float* bl  = (const float*)d_in[4];
    const float* Wr  = (const float*)d_in[5];
    const float* br  = (const float*)d_in[6];
    const float* att = (const float*)d_in[7];
    const float* gb  = (const float*)d_in[8];
    const float* Wo  = (const float*)d_in[9];
    const float* bo  = (const float*)d_in[10];
    const float* dp  = (const float*)d_in[11];
    float* out = (float*)d_out;
    const int* esrc = ei;
    const int* edst = ei + N_EDGES;

    // ws layout (16B-aligned segments):
    //  xl bf16[N*64] | xr bf16[N*64] | h bf16[N*64] | csr_src int[ETOT] |
    //  cnt int[NPAD] | cur int[NPAD] | offs int[NPAD] | bsum int[256] |
    //  wphi/wplo | wohi/wolo | wcol f32[128] | biasP f32[128]
    char* ws = (char*)d_ws;
    const size_t SZB = (size_t)N_NODES * H_DIM * sizeof(bf16);   // 6.4 MB
    bf16*  xl      = (bf16*)(ws);
    bf16*  xr      = (bf16*)(ws + SZB);
    bf16*  h       = (bf16*)(ws + 2 * SZB);
    int*   csr_src = (int*)(ws + 3 * SZB);
    int*   cnt     = (int*)(ws + 3 * SZB + (size_t)ETOT * 4);
    int*   cur     = cnt + NPAD;
    int*   offs    = cur + NPAD;
    int*   bsum    = offs + NPAD;
    bf16*  wphi    = (bf16*)(bsum + 256);
    bf16*  wplo    = wphi + 128 * WPS;
    bf16*  wohi    = wplo + 128 * WPS;
    bf16*  wolo    = wohi + 128 * WOS;
    float* wcol    = (float*)(wolo + 128 * WOS);
    float* biasP   = wcol + 128;

    hipMemsetAsync(cnt, 0, 2 * NPAD * sizeof(int), stream);

    prep_count_kernel<<<(N_EDGES + 255) / 256, 256, 0, stream>>>(
        Wl, bl, Wr, br, Wo, edst,
        wphi, wplo, wcol, biasP, wohi, wolo, cnt);

    proj_mfma<<<(N_NODES + 63) / 64, 256, 0, stream>>>(xf, xb, wphi, wplo,
                                                       wcol, biasP, xl, xr);

    scan_a_kernel<<<NPAD / 256, 256, 0, stream>>>(cnt, offs, bsum);
    scan_b_kernel<<<1, 256, 0, stream>>>(bsum);
    scan_c_kernel<<<NPAD / 256, 256, 0, stream>>>(offs, bsum);

    fill_kernel<<<(ETOT + 255) / 256, 256, 0, stream>>>(esrc, edst, offs, cur,
                                                        csr_src);

    agg_fused<<<(N_NODES * 64) / 256, 256, 0, stream>>>(csr_src, offs, xl, xr,
                                                        att, gb, h);

    out_mfma<<<(N_NODES + 63) / 64, 256, 0, stream>>>(h, wohi, wolo, bo, dp, out);
}

// Round 8
// 213.553 us; speedup vs baseline: 1.3789x; 1.1751x over previous
//
#include <hip/hip_runtime.h>
#include <hip/hip_bf16.h>
#include <math.h>

#define N_NODES 50000
#define N_EDGES 800000
#define F_DIM 128
#define H_DIM 64
#define IN_DIM 129   // F_DIM + 1 (binary feature)
#define NPAD 50176   // 196 * 256 (scan-padded node count)
#define WPS 136      // bf16 row stride, proj W  (16B-aligned rows)
#define WOS 72       // bf16 row stride, out W
#define ETOT (N_EDGES + N_NODES)   // 850000 CSR entries (self-loop per node)

typedef __hip_bfloat16 bf16;
typedef __attribute__((ext_vector_type(8))) short bf16x8;   // MFMA A/B frag (4 VGPR)
typedef __attribute__((ext_vector_type(4))) float f32x4;    // MFMA C/D frag

static __device__ __forceinline__ float b2f(bf16 x) { return __bfloat162float(x); }
static __device__ __forceinline__ float bs2f(short s) {
    union { float f; unsigned u; } c; c.u = ((unsigned)(unsigned short)s) << 16; return c.f;
}
static __device__ __forceinline__ short f2bs(float f) {
    union { bf16 b; short s; } u; u.b = __float2bfloat16(f); return u.s;
}

// ---------------------------------------------------------------------------
// P0 (merged prep + degree count + rank): W hi/lo split for MFMA, stacked
// bias, CSR degree histogram AND per-edge rank (rank write is coalesced).
// fill_kernel then needs no atomics at all.
// ---------------------------------------------------------------------------
__global__ __launch_bounds__(256) void prep_count_kernel(
    const float* __restrict__ Wl, const float* __restrict__ bl,
    const float* __restrict__ Wr, const float* __restrict__ br,
    const float* __restrict__ Wo, const int* __restrict__ edst,
    bf16* __restrict__ wphi, bf16* __restrict__ wplo,
    float* __restrict__ wcol, float* __restrict__ biasP,
    bf16* __restrict__ wohi, bf16* __restrict__ wolo,
    int* __restrict__ cnt, int* __restrict__ rank)
{
    int tid  = blockIdx.x * 256 + threadIdx.x;
    int nthr = gridDim.x * 256;

    if (tid < N_EDGES) rank[tid] = atomicAdd(&cnt[edst[tid]], 1);

    for (int idx = tid; idx < 128 * IN_DIM; idx += nthr) {
        int r = idx / IN_DIM, k = idx - r * IN_DIM;
        float v = (r < 64) ? Wl[r * IN_DIM + k] : Wr[(r - 64) * IN_DIM + k];
        if (k == 128) {
            wcol[r] = v;
        } else {
            bf16 hi = __float2bfloat16(v);
            wphi[r * WPS + k] = hi;
            wplo[r * WPS + k] = __float2bfloat16(v - b2f(hi));
        }
    }
    for (int idx = tid; idx < 128 * 64; idx += nthr) {
        int r = idx >> 6, k = idx & 63;
        float v = Wo[idx];
        bf16 hi = __float2bfloat16(v);
        wohi[r * WOS + k] = hi;
        wolo[r * WOS + k] = __float2bfloat16(v - b2f(hi));
    }
    if (tid < 128) biasP[tid] = (tid < 64) ? bl[tid] : br[tid - 64];
}

// ---------------------------------------------------------------------------
// K1 (MFMA): [xl|xr] = x @ [Wl;Wr]^T + bias.  B-frags in registers, no LDS.
// ---------------------------------------------------------------------------
__global__ __launch_bounds__(256) void proj_mfma(
    const float* __restrict__ xf, const float* __restrict__ xb,
    const bf16* __restrict__ wphi, const bf16* __restrict__ wplo,
    const float* __restrict__ wcol, const float* __restrict__ biasP,
    bf16* __restrict__ xl, bf16* __restrict__ xr)
{
    int wave = threadIdx.x >> 6;
    int lane = threadIdx.x & 63;
    int n = lane & 15, q = lane >> 4;
    int node0 = blockIdx.x * 64;

    bf16x8 bhi[2][4], blo[2][4];
    float biasv[2], w128[2];
    #pragma unroll
    for (int nt = 0; nt < 2; ++nt) {
        int ch = wave * 32 + nt * 16 + n;
        #pragma unroll
        for (int ks = 0; ks < 4; ++ks) {
            bhi[nt][ks] = *(const bf16x8*)(wphi + ch * WPS + ks * 32 + q * 8);
            blo[nt][ks] = *(const bf16x8*)(wplo + ch * WPS + ks * 32 + q * 8);
        }
        biasv[nt] = biasP[ch];
        w128[nt]  = wcol[ch];
    }

    #pragma unroll
    for (int mt = 0; mt < 4; ++mt) {
        int nb = node0 + mt * 16;
        if (nb >= N_NODES) break;
        const float* xrow = xf + (size_t)(nb + n) * F_DIM;
        bf16x8 a[4];
        #pragma unroll
        for (int ks = 0; ks < 4; ++ks) {
            float4 u = *(const float4*)(xrow + ks * 32 + q * 8);
            float4 v = *(const float4*)(xrow + ks * 32 + q * 8 + 4);
            bf16x8 t;
            t[0] = f2bs(u.x); t[1] = f2bs(u.y); t[2] = f2bs(u.z); t[3] = f2bs(u.w);
            t[4] = f2bs(v.x); t[5] = f2bs(v.y); t[6] = f2bs(v.z); t[7] = f2bs(v.w);
            a[ks] = t;
        }
        f32x4 acc[2] = {{0.f,0.f,0.f,0.f},{0.f,0.f,0.f,0.f}};
        #pragma unroll
        for (int ks = 0; ks < 4; ++ks) {
            #pragma unroll
            for (int nt = 0; nt < 2; ++nt) {
                acc[nt] = __builtin_amdgcn_mfma_f32_16x16x32_bf16(a[ks], bhi[nt][ks], acc[nt], 0, 0, 0);
                acc[nt] = __builtin_amdgcn_mfma_f32_16x16x32_bf16(a[ks], blo[nt][ks], acc[nt], 0, 0, 0);
            }
        }
        float4 xbv = *(const float4*)(xb + nb + q * 4);
        float xbr[4] = {xbv.x, xbv.y, xbv.z, xbv.w};
        #pragma unroll
        for (int nt = 0; nt < 2; ++nt) {
            int ch = wave * 32 + nt * 16 + n;
            bf16* dstp = (ch < 64) ? xl : xr;
            int cc = ch & 63;
            #pragma unroll
            for (int r = 0; r < 4; ++r) {
                int node = nb + q * 4 + r;   // C/D: row = quad*4 + reg
                float val = acc[nt][r] + xbr[r] * w128[nt] + biasv[nt];
                dstp[(size_t)node * H_DIM + cc] = __float2bfloat16(val);
            }
        }
    }
}

// ---------------------------------------------------------------------------
// CSR scan (deg+1 per node: slot offs[n] reserved for the self-loop).
// ---------------------------------------------------------------------------
__global__ __launch_bounds__(256) void scan_a_kernel(
    const int* __restrict__ cnt, int* __restrict__ offs, int* __restrict__ bsum)
{
    __shared__ int s[256];
    int tid = threadIdx.x;
    int i = blockIdx.x * 256 + tid;
    int v = (i < N_NODES) ? cnt[i] + 1 : 0;    // +1 = self-loop slot
    s[tid] = v;
    __syncthreads();
    #pragma unroll
    for (int d = 1; d < 256; d <<= 1) {
        int t = (tid >= d) ? s[tid - d] : 0;
        __syncthreads();
        s[tid] += t;
        __syncthreads();
    }
    offs[i] = s[tid] - v;
    if (tid == 255) bsum[blockIdx.x] = s[255];
}

__global__ __launch_bounds__(256) void scan_b_kernel(int* __restrict__ bsum)
{
    __shared__ int s[256];
    int tid = threadIdx.x;
    int v = (tid < 196) ? bsum[tid] : 0;
    s[tid] = v;
    __syncthreads();
    #pragma unroll
    for (int d = 1; d < 256; d <<= 1) {
        int t = (tid >= d) ? s[tid - d] : 0;
        __syncthreads();
        s[tid] += t;
        __syncthreads();
    }
    if (tid < 196) bsum[tid] = s[tid] - v;
}

__global__ __launch_bounds__(256) void scan_c_kernel(
    int* __restrict__ offs, const int* __restrict__ bsum)
{
    int i = blockIdx.x * 256 + threadIdx.x;
    offs[i] += bsum[blockIdx.x];
}

// ---------------------------------------------------------------------------
// K2a: CSR fill, atomic-free (rank precomputed in prep_count).
// id < E: real edge at slot offs[dst]+1+rank[id]; id >= E: self-loop of
// node id-E at slot offs[n].
// ---------------------------------------------------------------------------
__global__ __launch_bounds__(256) void fill_kernel(
    const int* __restrict__ esrc, const int* __restrict__ edst,
    const int* __restrict__ offs, const int* __restrict__ rank,
    int* __restrict__ csr_src)
{
    int id = blockIdx.x * 256 + threadIdx.x;
    if (id >= ETOT) return;
    int src, pos;
    if (id < N_EDGES) {
        src = esrc[id];
        pos = offs[edst[id]] + 1 + rank[id];
    } else {
        src = id - N_EDGES;
        pos = offs[src];
    }
    csr_src[pos] = src;
}

// ---------------------------------------------------------------------------
// K2b (fused score + aggregate, wave-per-dst, depth-2 pipeline):
// 2-D lane layout: g = lane>>3 (edge slot, 8/batch), c8 = lane&7 (channel
// octet). Indices fetched 2 batches ahead, values 1 batch ahead -> every
// iteration issues 2 INDEPENDENT loads (no serial idx->gather chain).
// Dot reduce = 3 shfl_xor per batch; group-combine once per dst.
// ---------------------------------------------------------------------------
__global__ __launch_bounds__(256) void agg_fused(
    const int* __restrict__ csr_src, const int* __restrict__ offs,
    const bf16* __restrict__ xl, const bf16* __restrict__ xr,
    const float* __restrict__ att, const float* __restrict__ gb,
    bf16* __restrict__ h)
{
    int wid  = (blockIdx.x * 256 + threadIdx.x) >> 6;   // dst node
    int lane = threadIdx.x & 63;
    if (wid >= N_NODES) return;
    int g  = lane >> 3;   // edge slot within batch
    int c8 = lane & 7;    // channel octet

    float attv[8], xrv[8];
    {
        bf16x8 xrow = *(const bf16x8*)(xr + (size_t)wid * H_DIM + c8 * 8);
        float4 a0 = *(const float4*)(att + c8 * 8);
        float4 a1 = *(const float4*)(att + c8 * 8 + 4);
        attv[0] = a0.x; attv[1] = a0.y; attv[2] = a0.z; attv[3] = a0.w;
        attv[4] = a1.x; attv[5] = a1.y; attv[6] = a1.z; attv[7] = a1.w;
        #pragma unroll
        for (int j = 0; j < 8; ++j) xrv[j] = bs2f(xrow[j]);
    }

    int beg = offs[wid], end = offs[wid + 1];   // end-beg >= 1 (self-loop)
    int last = end - 1;
    float den = 0.f;
    float acc[8] = {0.f, 0.f, 0.f, 0.f, 0.f, 0.f, 0.f, 0.f};

    int i0 = beg + g;       i0 = (i0 < end) ? i0 : last;
    int i1 = beg + 8 + g;   i1 = (i1 < end) ? i1 : last;
    int srcB = csr_src[i1];                      // index for batch 1
    bf16x8 xa = *(const bf16x8*)(xl + (size_t)csr_src[i0] * H_DIM + c8 * 8);

    for (int base = beg; base < end; base += 8) {
        // issue both independent loads up front
        int i2 = base + 16 + g;  i2 = (i2 < end) ? i2 : last;
        int srcC = csr_src[i2];                               // index batch+2
        bf16x8 xb = *(const bf16x8*)(xl + (size_t)srcB * H_DIM + c8 * 8); // value batch+1

        bool valid = (base + g) < end;
        float xv[8], p = 0.f;
        #pragma unroll
        for (int j = 0; j < 8; ++j) {
            xv[j] = bs2f(xa[j]);
            float m = xv[j] + xrv[j];
            m = (m > 0.f) ? m : 0.2f * m;
            p += m * attv[j];
        }
        p += __shfl_xor(p, 1);
        p += __shfl_xor(p, 2);
        p += __shfl_xor(p, 4);      // all lanes of group g now hold p_g
        float ex = valid ? __expf(p) : 0.f;
        den += ex;
        #pragma unroll
        for (int j = 0; j < 8; ++j) acc[j] += ex * xv[j];

        xa = xb;
        srcB = srcC;
    }

    // combine the 8 edge-groups (once per dst)
    #pragma unroll
    for (int j = 0; j < 8; ++j) {
        acc[j] += __shfl_xor(acc[j], 8);
        acc[j] += __shfl_xor(acc[j], 16);
        acc[j] += __shfl_xor(acc[j], 32);
    }
    den += __shfl_xor(den, 8);
    den += __shfl_xor(den, 16);
    den += __shfl_xor(den, 32);

    if (g == 0) {
        float inv = 1.0f / den;
        float4 g0 = *(const float4*)(gb + c8 * 8);
        float4 g1 = *(const float4*)(gb + c8 * 8 + 4);
        float gbv[8] = {g0.x, g0.y, g0.z, g0.w, g1.x, g1.y, g1.z, g1.w};
        bf16x8 ov;
        #pragma unroll
        for (int j = 0; j < 8; ++j) {
            float v = acc[j] * inv + gbv[j];
            v = (v > 0.f) ? v : expm1f(v);
            ov[j] = f2bs(v);
        }
        *(bf16x8*)(h + (size_t)wid * H_DIM + c8 * 8) = ov;
    }
}

// ---------------------------------------------------------------------------
// K3 (MFMA): logits = h @ Wo^T + bo (+ softplus(dispersion) tail on block 0).
// ---------------------------------------------------------------------------
__global__ __launch_bounds__(256) void out_mfma(
    const bf16* __restrict__ h,
    const bf16* __restrict__ wohi, const bf16* __restrict__ wolo,
    const float* __restrict__ bo, const float* __restrict__ disp,
    float* __restrict__ out)
{
    if (blockIdx.x == 0 && threadIdx.x < F_DIM) {
        float d = disp[threadIdx.x];
        out[(size_t)N_NODES * F_DIM + threadIdx.x] = (d > 20.f) ? d : log1pf(__expf(d));
    }

    int wave = threadIdx.x >> 6;
    int lane = threadIdx.x & 63;
    int n = lane & 15, q = lane >> 4;
    int node0 = blockIdx.x * 64;

    bf16x8 bhi[2][2], blo[2][2];
    float bov[2];
    #pragma unroll
    for (int nt = 0; nt < 2; ++nt) {
        int ch = wave * 32 + nt * 16 + n;
        #pragma unroll
        for (int ks = 0; ks < 2; ++ks) {
            bhi[nt][ks] = *(const bf16x8*)(wohi + ch * WOS + ks * 32 + q * 8);
            blo[nt][ks] = *(const bf16x8*)(wolo + ch * WOS + ks * 32 + q * 8);
        }
        bov[nt] = bo[ch];
    }

    #pragma unroll
    for (int mt = 0; mt < 4; ++mt) {
        int nb = node0 + mt * 16;
        if (nb >= N_NODES) break;
        const bf16* hrow = h + (size_t)(nb + n) * H_DIM;
        bf16x8 a[2];
        #pragma unroll
        for (int ks = 0; ks < 2; ++ks)
            a[ks] = *(const bf16x8*)(hrow + ks * 32 + q * 8);
        f32x4 acc[2] = {{0.f,0.f,0.f,0.f},{0.f,0.f,0.f,0.f}};
        #pragma unroll
        for (int ks = 0; ks < 2; ++ks) {
            #pragma unroll
            for (int nt = 0; nt < 2; ++nt) {
                acc[nt] = __builtin_amdgcn_mfma_f32_16x16x32_bf16(a[ks], bhi[nt][ks], acc[nt], 0, 0, 0);
                acc[nt] = __builtin_amdgcn_mfma_f32_16x16x32_bf16(a[ks], blo[nt][ks], acc[nt], 0, 0, 0);
            }
        }
        #pragma unroll
        for (int nt = 0; nt < 2; ++nt) {
            int ch = wave * 32 + nt * 16 + n;
            #pragma unroll
            for (int r = 0; r < 4; ++r) {
                int node = nb + q * 4 + r;
                out[(size_t)node * F_DIM + ch] = acc[nt][r] + bov[nt];
            }
        }
    }
}

// ---------------------------------------------------------------------------
extern "C" void kernel_launch(void* const* d_in, const int* in_sizes, int n_in,
                              void* d_out, int out_size, void* d_ws, size_t ws_size,
                              hipStream_t stream)
{
    const float* xf  = (const float*)d_in[0];
    const float* xb  = (const float*)d_in[1];
    const int*   ei  = (const int*)d_in[2];    // [2, E] int32, row-major
    const float* Wl  = (const float*)d_in[3];
    const float* bl  = (const float*)d_in[4];
    const float* Wr  = (const float*)d_in[5];
    const float* br  = (const float*)d_in[6];
    const float* att = (const float*)d_in[7];
    const float* gb  = (const float*)d_in[8];
    const float* Wo  = (const float*)d_in[9];
    const float* bo  = (const float*)d_in[10];
    const float* dp  = (const float*)d_in[11];
    float* out = (float*)d_out;
    const int* esrc = ei;
    const int* edst = ei + N_EDGES;

    // ws layout (16B-aligned segments):
    //  xl bf16[N*64] | xr bf16[N*64] | h bf16[N*64] | csr_src int[ETOT] |
    //  rank int[E] | cnt int[NPAD] | offs int[NPAD] | bsum int[256] |
    //  wphi/wplo | wohi/wolo | wcol f32[128] | biasP f32[128]
    char* ws = (char*)d_ws;
    const size_t SZB = (size_t)N_NODES * H_DIM * sizeof(bf16);   // 6.4 MB
    bf16*  xl      = (bf16*)(ws);
    bf16*  xr      = (bf16*)(ws + SZB);
    bf16*  h       = (bf16*)(ws + 2 * SZB);
    int*   csr_src = (int*)(ws + 3 * SZB);
    int*   rank    = (int*)(ws + 3 * SZB + (size_t)ETOT * 4);
    int*   cnt     = rank + N_EDGES;
    int*   offs    = cnt + NPAD;
    int*   bsum    = offs + NPAD;
    bf16*  wphi    = (bf16*)(bsum + 256);
    bf16*  wplo    = wphi + 128 * WPS;
    bf16*  wohi    = wplo + 128 * WPS;
    bf16*  wolo    = wohi + 128 * WOS;
    float* wcol    = (float*)(wolo + 128 * WOS);
    float* biasP   = wcol + 128;

    hipMemsetAsync(cnt, 0, NPAD * sizeof(int), stream);

    prep_count_kernel<<<(N_EDGES + 255) / 256, 256, 0, stream>>>(
        Wl, bl, Wr, br, Wo, edst,
        wphi, wplo, wcol, biasP, wohi, wolo, cnt, rank);

    proj_mfma<<<(N_NODES + 63) / 64, 256, 0, stream>>>(xf, xb, wphi, wplo,
                                                       wcol, biasP, xl, xr);

    scan_a_kernel<<<NPAD / 256, 256, 0, stream>>>(cnt, offs, bsum);
    scan_b_kernel<<<1, 256, 0, stream>>>(bsum);
    scan_c_kernel<<<NPAD / 256, 256, 0, stream>>>(offs, bsum);

    fill_kernel<<<(ETOT + 255) / 256, 256, 0, stream>>>(esrc, edst, offs, rank,
                                                        csr_src);

    agg_fused<<<(N_NODES * 64) / 256, 256, 0, stream>>>(csr_src, offs, xl, xr,
                                                        att, gb, h);

    out_mfma<<<(N_NODES + 63) / 64, 256, 0, stream>>>(h, wohi, wolo, bo, dp, out);
}

// Round 9
// 201.451 us; speedup vs baseline: 1.4617x; 1.0601x over previous
//
#include <hip/hip_runtime.h>
#include <hip/hip_bf16.h>
#include <math.h>

#define N_NODES 50000
#define N_EDGES 800000
#define F_DIM 128
#define H_DIM 64
#define IN_DIM 129   // F_DIM + 1 (binary feature)
#define NPAD 50176   // 196 * 256 (scan-padded node count)
#define ETOT (N_EDGES + N_NODES)          // 850000 CSR entries
#define PROJ_BLKS ((N_NODES + 63) / 64)   // 782
#define CNT_BLKS  ((N_EDGES + 255) / 256) // 3125

typedef __hip_bfloat16 bf16;
typedef __attribute__((ext_vector_type(8))) short bf16x8;   // MFMA A/B frag (4 VGPR)
typedef __attribute__((ext_vector_type(4))) float f32x4;    // MFMA C/D frag

static __device__ __forceinline__ float bs2f(short s) {
    union { float f; unsigned u; } c; c.u = ((unsigned)(unsigned short)s) << 16; return c.f;
}
static __device__ __forceinline__ short f2bs(float f) {
    union { bf16 b; short s; } u; u.b = __float2bfloat16(f); return u.s;
}

// ---------------------------------------------------------------------------
// Phase 1 (hybrid dispatch — overlap two independent jobs):
//  blocks [0, PROJ_BLKS):            [xl|xr] = x @ [Wl;Wr]^T + bias (MFMA)
//  blocks [PROJ_BLKS, +CNT_BLKS):    CSR degree histogram + per-edge rank
// Proj builds its W hi/lo B-frags in registers straight from f32 W (L2-hot
// scalar loads, once per block); count's scattered atomics hide under
// proj's VALU/MFMA occupancy on the same CUs.
// ---------------------------------------------------------------------------
__global__ __launch_bounds__(256) void phase1_kernel(
    const float* __restrict__ xf, const float* __restrict__ xb,
    const float* __restrict__ Wl, const float* __restrict__ bl,
    const float* __restrict__ Wr, const float* __restrict__ br,
    const int* __restrict__ edst,
    bf16* __restrict__ xl, bf16* __restrict__ xr,
    int* __restrict__ cnt, int* __restrict__ rank)
{
    if (blockIdx.x >= PROJ_BLKS) {
        int e = (blockIdx.x - PROJ_BLKS) * 256 + threadIdx.x;
        if (e < N_EDGES) rank[e] = atomicAdd(&cnt[edst[e]], 1);
        return;
    }

    int wave = threadIdx.x >> 6;
    int lane = threadIdx.x & 63;
    int n = lane & 15, q = lane >> 4;
    int node0 = blockIdx.x * 64;

    // Build B-frags (hi/lo split of W rows) in registers from f32 W.
    bf16x8 bhi[2][4], blo[2][4];
    float biasv[2], w128[2];
    #pragma unroll
    for (int nt = 0; nt < 2; ++nt) {
        int ch = wave * 32 + nt * 16 + n;
        const float* wrow = (ch < 64) ? (Wl + (size_t)ch * IN_DIM)
                                      : (Wr + (size_t)(ch - 64) * IN_DIM);
        #pragma unroll
        for (int ks = 0; ks < 4; ++ks) {
            bf16x8 hi, lo;
            #pragma unroll
            for (int j = 0; j < 8; ++j) {
                float v = wrow[ks * 32 + q * 8 + j];
                short hs = f2bs(v);
                hi[j] = hs;
                lo[j] = f2bs(v - bs2f(hs));
            }
            bhi[nt][ks] = hi;
            blo[nt][ks] = lo;
        }
        biasv[nt] = (ch < 64) ? bl[ch] : br[ch - 64];
        w128[nt]  = wrow[128];
    }

    #pragma unroll
    for (int mt = 0; mt < 4; ++mt) {
        int nb = node0 + mt * 16;
        if (nb >= N_NODES) break;
        const float* xrow = xf + (size_t)(nb + n) * F_DIM;
        bf16x8 a[4];
        #pragma unroll
        for (int ks = 0; ks < 4; ++ks) {
            float4 u = *(const float4*)(xrow + ks * 32 + q * 8);
            float4 v = *(const float4*)(xrow + ks * 32 + q * 8 + 4);
            bf16x8 t;
            t[0] = f2bs(u.x); t[1] = f2bs(u.y); t[2] = f2bs(u.z); t[3] = f2bs(u.w);
            t[4] = f2bs(v.x); t[5] = f2bs(v.y); t[6] = f2bs(v.z); t[7] = f2bs(v.w);
            a[ks] = t;
        }
        f32x4 acc[2] = {{0.f,0.f,0.f,0.f},{0.f,0.f,0.f,0.f}};
        #pragma unroll
        for (int ks = 0; ks < 4; ++ks) {
            #pragma unroll
            for (int nt = 0; nt < 2; ++nt) {
                acc[nt] = __builtin_amdgcn_mfma_f32_16x16x32_bf16(a[ks], bhi[nt][ks], acc[nt], 0, 0, 0);
                acc[nt] = __builtin_amdgcn_mfma_f32_16x16x32_bf16(a[ks], blo[nt][ks], acc[nt], 0, 0, 0);
            }
        }
        float4 xbv = *(const float4*)(xb + nb + q * 4);
        float xbr[4] = {xbv.x, xbv.y, xbv.z, xbv.w};
        #pragma unroll
        for (int nt = 0; nt < 2; ++nt) {
            int ch = wave * 32 + nt * 16 + n;
            bf16* dstp = (ch < 64) ? xl : xr;
            int cc = ch & 63;
            #pragma unroll
            for (int r = 0; r < 4; ++r) {
                int node = nb + q * 4 + r;   // C/D: row = quad*4 + reg
                float val = acc[nt][r] + xbr[r] * w128[nt] + biasv[nt];
                dstp[(size_t)node * H_DIM + cc] = __float2bfloat16(val);
            }
        }
    }
}

// ---------------------------------------------------------------------------
// CSR scan (deg+1 per node: slot 0 of each segment = self-loop).
// Block-local exclusive scan; bsum holds per-block totals, made exclusive by
// scan_b. Consumers add bsum[node>>8] at use (scan_c eliminated).
// ---------------------------------------------------------------------------
__global__ __launch_bounds__(256) void scan_a_kernel(
    const int* __restrict__ cnt, int* __restrict__ offs, int* __restrict__ bsum)
{
    __shared__ int s[256];
    int tid = threadIdx.x;
    int i = blockIdx.x * 256 + tid;
    int v = (i < N_NODES) ? cnt[i] + 1 : 0;    // +1 = self-loop slot
    s[tid] = v;
    __syncthreads();
    #pragma unroll
    for (int d = 1; d < 256; d <<= 1) {
        int t = (tid >= d) ? s[tid - d] : 0;
        __syncthreads();
        s[tid] += t;
        __syncthreads();
    }
    offs[i] = s[tid] - v;
    if (tid == 255) bsum[blockIdx.x] = s[255];
}

__global__ __launch_bounds__(256) void scan_b_kernel(int* __restrict__ bsum)
{
    __shared__ int s[256];
    int tid = threadIdx.x;
    int v = (tid < 196) ? bsum[tid] : 0;
    s[tid] = v;
    __syncthreads();
    #pragma unroll
    for (int d = 1; d < 256; d <<= 1) {
        int t = (tid >= d) ? s[tid - d] : 0;
        __syncthreads();
        s[tid] += t;
        __syncthreads();
    }
    if (tid < 196) bsum[tid] = s[tid] - v;
}

// ---------------------------------------------------------------------------
// K2a: CSR fill, atomic-free (rank from phase1, block offset from bsum).
// ---------------------------------------------------------------------------
__global__ __launch_bounds__(256) void fill_kernel(
    const int* __restrict__ esrc, const int* __restrict__ edst,
    const int* __restrict__ offs, const int* __restrict__ bsum,
    const int* __restrict__ rank, int* __restrict__ csr_src)
{
    int id = blockIdx.x * 256 + threadIdx.x;
    if (id >= ETOT) return;
    int src, pos;
    if (id < N_EDGES) {
        src = esrc[id];
        int dst = edst[id];
        pos = offs[dst] + bsum[dst >> 8] + 1 + rank[id];
    } else {
        src = id - N_EDGES;
        pos = offs[src] + bsum[src >> 8];
    }
    csr_src[pos] = src;
}

// ---------------------------------------------------------------------------
// K2b (fused score + aggregate, wave-per-dst, depth-3 pipeline):
// 2-D lane layout: g = lane>>3 (edge slot, 8/batch), c8 = lane&7 (channel
// octet). Values for batches +1 and +2 in flight; indices for +3.
// Dot reduce = 3 shfl_xor per batch; group-combine once per dst.
// ---------------------------------------------------------------------------
__global__ __launch_bounds__(256) void agg_fused(
    const int* __restrict__ csr_src, const int* __restrict__ offs,
    const int* __restrict__ bsum,
    const bf16* __restrict__ xl, const bf16* __restrict__ xr,
    const float* __restrict__ att, const float* __restrict__ gb,
    bf16* __restrict__ h)
{
    int wid  = (blockIdx.x * 256 + threadIdx.x) >> 6;   // dst node
    int lane = threadIdx.x & 63;
    if (wid >= N_NODES) return;
    int g  = lane >> 3;   // edge slot within batch
    int c8 = lane & 7;    // channel octet

    float attv[8], xrv[8];
    {
        bf16x8 xrow = *(const bf16x8*)(xr + (size_t)wid * H_DIM + c8 * 8);
        float4 a0 = *(const float4*)(att + c8 * 8);
        float4 a1 = *(const float4*)(att + c8 * 8 + 4);
        attv[0] = a0.x; attv[1] = a0.y; attv[2] = a0.z; attv[3] = a0.w;
        attv[4] = a1.x; attv[5] = a1.y; attv[6] = a1.z; attv[7] = a1.w;
        #pragma unroll
        for (int j = 0; j < 8; ++j) xrv[j] = bs2f(xrow[j]);
    }

    int beg = offs[wid] + bsum[wid >> 8];
    int end = offs[wid + 1] + bsum[(wid + 1) >> 8];   // >= beg+1 (self-loop)
    int last = end - 1;
    float den = 0.f;
    float acc[8] = {0.f, 0.f, 0.f, 0.f, 0.f, 0.f, 0.f, 0.f};

    int i0 = beg + g;        i0 = (i0 < end) ? i0 : last;
    int i1 = beg + 8 + g;    i1 = (i1 < end) ? i1 : last;
    int i2 = beg + 16 + g;   i2 = (i2 < end) ? i2 : last;
    int srcC = csr_src[i2];                                    // idx batch+2
    bf16x8 xa = *(const bf16x8*)(xl + (size_t)csr_src[i0] * H_DIM + c8 * 8);
    bf16x8 xb = *(const bf16x8*)(xl + (size_t)csr_src[i1] * H_DIM + c8 * 8);

    for (int base = beg; base < end; base += 8) {
        int i3 = base + 24 + g;  i3 = (i3 < end) ? i3 : last;
        int srcD = csr_src[i3];                                // idx batch+3
        bf16x8 xc = *(const bf16x8*)(xl + (size_t)srcC * H_DIM + c8 * 8);

        bool valid = (base + g) < end;
        float xv[8], p = 0.f;
        #pragma unroll
        for (int j = 0; j < 8; ++j) {
            xv[j] = bs2f(xa[j]);
            float m = xv[j] + xrv[j];
            m = (m > 0.f) ? m : 0.2f * m;
            p += m * attv[j];
        }
        p += __shfl_xor(p, 1);
        p += __shfl_xor(p, 2);
        p += __shfl_xor(p, 4);      // all lanes of group g now hold p_g
        float ex = valid ? __expf(p) : 0.f;
        den += ex;
        #pragma unroll
        for (int j = 0; j < 8; ++j) acc[j] += ex * xv[j];

        xa = xb;
        xb = xc;
        srcC = srcD;
    }

    // combine the 8 edge-groups (once per dst)
    #pragma unroll
    for (int j = 0; j < 8; ++j) {
        acc[j] += __shfl_xor(acc[j], 8);
        acc[j] += __shfl_xor(acc[j], 16);
        acc[j] += __shfl_xor(acc[j], 32);
    }
    den += __shfl_xor(den, 8);
    den += __shfl_xor(den, 16);
    den += __shfl_xor(den, 32);

    if (g == 0) {
        float inv = 1.0f / den;
        float4 g0 = *(const float4*)(gb + c8 * 8);
        float4 g1 = *(const float4*)(gb + c8 * 8 + 4);
        float gbv[8] = {g0.x, g0.y, g0.z, g0.w, g1.x, g1.y, g1.z, g1.w};
        bf16x8 ov;
        #pragma unroll
        for (int j = 0; j < 8; ++j) {
            float v = acc[j] * inv + gbv[j];
            v = (v > 0.f) ? v : expm1f(v);
            ov[j] = f2bs(v);
        }
        *(bf16x8*)(h + (size_t)wid * H_DIM + c8 * 8) = ov;
    }
}

// ---------------------------------------------------------------------------
// K3 (MFMA): logits = h @ Wo^T + bo (+ softplus(dispersion) tail on block 0).
// B-frags (Wo hi/lo) built in registers from f32 Wo (rows 256 B aligned ->
// float4 loads), once per block.
// ---------------------------------------------------------------------------
__global__ __launch_bounds__(256) void out_mfma(
    const bf16* __restrict__ h, const float* __restrict__ Wo,
    const float* __restrict__ bo, const float* __restrict__ disp,
    float* __restrict__ out)
{
    if (blockIdx.x == 0 && threadIdx.x < F_DIM) {
        float d = disp[threadIdx.x];
        out[(size_t)N_NODES * F_DIM + threadIdx.x] = (d > 20.f) ? d : log1pf(__expf(d));
    }

    int wave = threadIdx.x >> 6;
    int lane = threadIdx.x & 63;
    int n = lane & 15, q = lane >> 4;
    int node0 = blockIdx.x * 64;

    bf16x8 bhi[2][2], blo[2][2];
    float bov[2];
    #pragma unroll
    for (int nt = 0; nt < 2; ++nt) {
        int ch = wave * 32 + nt * 16 + n;
        const float* wrow = Wo + (size_t)ch * H_DIM;
        #pragma unroll
        for (int ks = 0; ks < 2; ++ks) {
            float4 u = *(const float4*)(wrow + ks * 32 + q * 8);
            float4 v = *(const float4*)(wrow + ks * 32 + q * 8 + 4);
            float w[8] = {u.x, u.y, u.z, u.w, v.x, v.y, v.z, v.w};
            bf16x8 hi, lo;
            #pragma unroll
            for (int j = 0; j < 8; ++j) {
                short hs = f2bs(w[j]);
                hi[j] = hs;
                lo[j] = f2bs(w[j] - bs2f(hs));
            }
            bhi[nt][ks] = hi;
            blo[nt][ks] = lo;
        }
        bov[nt] = bo[ch];
    }

    #pragma unroll
    for (int mt = 0; mt < 4; ++mt) {
        int nb = node0 + mt * 16;
        if (nb >= N_NODES) break;
        const bf16* hrow = h + (size_t)(nb + n) * H_DIM;
        bf16x8 a[2];
        #pragma unroll
        for (int ks = 0; ks < 2; ++ks)
            a[ks] = *(const bf16x8*)(hrow + ks * 32 + q * 8);
        f32x4 acc[2] = {{0.f,0.f,0.f,0.f},{0.f,0.f,0.f,0.f}};
        #pragma unroll
        for (int ks = 0; ks < 2; ++ks) {
            #pragma unroll
            for (int nt = 0; nt < 2; ++nt) {
                acc[nt] = __builtin_amdgcn_mfma_f32_16x16x32_bf16(a[ks], bhi[nt][ks], acc[nt], 0, 0, 0);
                acc[nt] = __builtin_amdgcn_mfma_f32_16x16x32_bf16(a[ks], blo[nt][ks], acc[nt], 0, 0, 0);
            }
        }
        #pragma unroll
        for (int nt = 0; nt < 2; ++nt) {
            int ch = wave * 32 + nt * 16 + n;
            #pragma unroll
            for (int r = 0; r < 4; ++r) {
                int node = nb + q * 4 + r;
                out[(size_t)node * F_DIM + ch] = acc[nt][r] + bov[nt];
            }
        }
    }
}

// ---------------------------------------------------------------------------
extern "C" void kernel_launch(void* const* d_in, const int* in_sizes, int n_in,
                              void* d_out, int out_size, void* d_ws, size_t ws_size,
                              hipStream_t stream)
{
    const float* xf  = (const float*)d_in[0];
    const float* xb  = (const float*)d_in[1];
    const int*   ei  = (const int*)d_in[2];    // [2, E] int32, row-major
    const float* Wl  = (const float*)d_in[3];
    const float* bl  = (const float*)d_in[4];
    const float* Wr  = (const float*)d_in[5];
    const float* br  = (const float*)d_in[6];
    const float* att = (const float*)d_in[7];
    const float* gb  = (const float*)d_in[8];
    const float* Wo  = (const float*)d_in[9];
    const float* bo  = (const float*)d_in[10];
    const float* dp  = (const float*)d_in[11];
    float* out = (float*)d_out;
    const int* esrc = ei;
    const int* edst = ei + N_EDGES;

    // ws layout (16B-aligned segments):
    //  xl bf16[N*64] | xr bf16[N*64] | h bf16[N*64] | csr_src int[ETOT] |
    //  rank int[E] | cnt int[NPAD] | offs int[NPAD] | bsum int[256]
    char* ws = (char*)d_ws;
    const size_t SZB = (size_t)N_NODES * H_DIM * sizeof(bf16);   // 6.4 MB
    bf16*  xl      = (bf16*)(ws);
    bf16*  xr      = (bf16*)(ws + SZB);
    bf16*  h       = (bf16*)(ws + 2 * SZB);
    int*   csr_src = (int*)(ws + 3 * SZB);
    int*   rank    = (int*)(ws + 3 * SZB + (size_t)ETOT * 4);
    int*   cnt     = rank + N_EDGES;
    int*   offs    = cnt + NPAD;
    int*   bsum    = offs + NPAD;

    hipMemsetAsync(cnt, 0, NPAD * sizeof(int), stream);

    phase1_kernel<<<PROJ_BLKS + CNT_BLKS, 256, 0, stream>>>(
        xf, xb, Wl, bl, Wr, br, edst, xl, xr, cnt, rank);

    scan_a_kernel<<<NPAD / 256, 256, 0, stream>>>(cnt, offs, bsum);
    scan_b_kernel<<<1, 256, 0, stream>>>(bsum);

    fill_kernel<<<(ETOT + 255) / 256, 256, 0, stream>>>(esrc, edst, offs, bsum,
                                                        rank, csr_src);

    agg_fused<<<(N_NODES * 64) / 256, 256, 0, stream>>>(csr_src, offs, bsum,
                                                        xl, xr, att, gb, h);

    out_mfma<<<(N_NODES + 63) / 64, 256, 0, stream>>>(h, Wo, bo, dp, out);
}